// Round 18
// baseline (211.768 us; speedup 1.0000x reference)
//
#include <hip/hip_runtime.h>
#include <stdint.h>

// 2-layer tanh RNN, fused, f32, single-wave blocks, GB=3.
// R18: ASM-SCHEDULED INNER LOOP with counted lgkmcnt waits.
//   R14-R17 showed the compiler will not software-pipeline the LDS
//   round-trip (reads sink to uses; 340 stall cyc/iter). Fix per the
//   8-phase GEMM discipline: all in-loop DS ops live in asm volatile
//   blocks; counted s_waitcnt lgkmcnt(7)/(6) (never 0) keep reads in
//   flight across the loop back-edge; sched_barrier(0) after each wait
//   (rule 18) stops the scheduler from moving uses across.
//   Per-iter: layer0 dots+a1 dots (use old state) -> tanh0 -> A-block
//   {write h0[i]; read h0-state; read x[i+1]} -> lgkmcnt(7) [prev B done]
//   -> a2 dots -> tanh1 -> B-block {write h1[i-1]; read h1-state}
//   -> lgkmcnt(6) [A done] -> next iter. Latency covered by real work.

#define Bsz 4096
#define Tn  512
#define Hn  20
#define GB  3
#define XPAD 520
#define NTHREADS 64

typedef float v2 __attribute__((ext_vector_type(2)));

__device__ __forceinline__ float tanh_fast(float v) {
    float e = __expf(2.0f * v);
    return 1.0f - 2.0f * __builtin_amdgcn_rcpf(e + 1.0f);
}

// packed 20-dot against float4 state tiles, two accumulator chains
#define DOT20Q(acc, accb, W, C0, C1, C2, C3, C4) do { \
    acc  = __builtin_elementwise_fma(W##0, (v2){(C0).x,(C0).y}, acc);  \
    accb = __builtin_elementwise_fma(W##1, (v2){(C0).z,(C0).w}, accb); \
    acc  = __builtin_elementwise_fma(W##2, (v2){(C1).x,(C1).y}, acc);  \
    accb = __builtin_elementwise_fma(W##3, (v2){(C1).z,(C1).w}, accb); \
    acc  = __builtin_elementwise_fma(W##4, (v2){(C2).x,(C2).y}, acc);  \
    accb = __builtin_elementwise_fma(W##5, (v2){(C2).z,(C2).w}, accb); \
    acc  = __builtin_elementwise_fma(W##6, (v2){(C3).x,(C3).y}, acc);  \
    accb = __builtin_elementwise_fma(W##7, (v2){(C3).z,(C3).w}, accb); \
    acc  = __builtin_elementwise_fma(W##8, (v2){(C4).x,(C4).y}, acc);  \
    accb = __builtin_elementwise_fma(W##9, (v2){(C4).z,(C4).w}, accb); \
} while (0)

#define LOAD_ROWP(W, ptr) \
    v2 W##0, W##1, W##2, W##3, W##4, W##5, W##6, W##7, W##8, W##9; \
    { const float4* _p = (const float4*)(ptr); \
      float4 _t; \
      _t = _p[0]; W##0 = (v2){_t.x, _t.y}; W##1 = (v2){_t.z, _t.w}; \
      _t = _p[1]; W##2 = (v2){_t.x, _t.y}; W##3 = (v2){_t.z, _t.w}; \
      _t = _p[2]; W##4 = (v2){_t.x, _t.y}; W##5 = (v2){_t.z, _t.w}; \
      _t = _p[3]; W##6 = (v2){_t.x, _t.y}; W##7 = (v2){_t.z, _t.w}; \
      _t = _p[4]; W##8 = (v2){_t.x, _t.y}; W##9 = (v2){_t.z, _t.w}; }

__global__ __launch_bounds__(NTHREADS)
__attribute__((amdgpu_waves_per_eu(1, 2)))
void rnn2_fused(const float* __restrict__ x,        // [B,T,1]
                const float* __restrict__ hidden,   // [2,B,H]
                const float* __restrict__ W_ih0,    // [H,1]
                const float* __restrict__ W_hh0,    // [H,H]
                const float* __restrict__ b_ih0,    // [H]
                const float* __restrict__ b_hh0,    // [H]
                const float* __restrict__ W_ih1,    // [H,H]
                const float* __restrict__ W_hh1,    // [H,H]
                const float* __restrict__ b_ih1,    // [H]
                const float* __restrict__ b_hh1,    // [H]
                const float* __restrict__ fc_w,     // [1,H]
                const float* __restrict__ fc_b,     // [1]
                float* __restrict__ out)            // [B] ++ [2,B,H] flat
{
    const int tid = threadIdx.x;
    int g = tid / Hn;                  // 0..3
    int j = tid - g * Hn;              // 0..19
    const bool lane_ok = (tid < GB * Hn);
    if (!lane_ok) { g = GB - 1; j = tid - 60; }  // lanes 60..63 dup batch 2
                                       // (same-addr same-data writes: benign)
    const int  b        = blockIdx.x * GB + g;
    const bool b_ok     = (b < Bsz);
    const int  bl       = b_ok ? b : (Bsz - 1);
    const bool store_ok = lane_ok && b_ok;

    __shared__ __align__(16) float xs[GB][XPAD];   // 6.24 KB
    __shared__ __align__(16) float hs[2][GB][Hn];  // state mailboxes

    // ---- weights as 30 loop-invariant v2 SSA values
    LOAD_ROWP(w0, W_hh0 + j * Hn)
    LOAD_ROWP(w1, W_ih1 + j * Hn)
    LOAD_ROWP(w2, W_hh1 + j * Hn)
    const float wih0  = W_ih0[j];
    const float bias0 = b_ih0[j] + b_hh0[j];
    const float bias1 = b_ih1[j] + b_hh1[j];

    // ---- stage ALL x (coalesced float4; clamped batch rows)
    {
        const int bB = blockIdx.x * GB;
        #pragma unroll
        for (int r = 0; r < (GB * Tn) / (NTHREADS * 4); ++r) {  // 6 rounds
            const int c  = (r * NTHREADS + tid) * 4;
            const int gg = c >> 9;
            const int t  = c & (Tn - 1);
            const int bb = (bB + gg < Bsz) ? (bB + gg) : (Bsz - 1);
            float4 v = *(const float4*)(x + (long)bb * Tn + t);
            *(float4*)&xs[gg][t] = v;
        }
    }

    // ---- init state mailboxes
    const float h1i = hidden[(long)Bsz * Hn + bl * Hn + j];
    hs[0][g][j] = hidden[bl * Hn + j];
    hs[1][g][j] = h1i;

    // ---- LDS byte addresses (generic->LDS offset truncation)
    uint32_t h0_base = (uint32_t)(uintptr_t)&hs[0][g][0];
    uint32_t h0_mine = (uint32_t)(uintptr_t)&hs[0][g][j];
    uint32_t h1_base = (uint32_t)(uintptr_t)&hs[1][g][0];
    uint32_t h1_mine = (uint32_t)(uintptr_t)&hs[1][g][j];
    uint32_t x_addr  = (uint32_t)(uintptr_t)&xs[g][2];   // iter1 A reads x[2]

    // ---- prologue (C++ LDS ok, pre-asm): h0[0]
    float n0_keep;
    {
        const float4 p0 = *(const float4*)&hs[0][g][0];
        const float4 p1 = *(const float4*)&hs[0][g][4];
        const float4 p2 = *(const float4*)&hs[0][g][8];
        const float4 p3 = *(const float4*)&hs[0][g][12];
        const float4 p4 = *(const float4*)&hs[0][g][16];
        v2 a0  = (v2){fmaf(xs[g][0], wih0, bias0), 0.f};
        v2 a0b = (v2){0.f, 0.f};
        DOT20Q(a0, a0b, w0, p0, p1, p2, p3, p4);
        const v2 s0 = a0 + a0b;
        n0_keep = tanh_fast(s0.x + s0.y);
    }

    // drain all compiler DS ops so counted waits below are exact
    asm volatile("s_waitcnt lgkmcnt(0)" ::: "memory");
    __builtin_amdgcn_sched_barrier(0);

    float4 c0, c1, c2, c3, c4;   // h0-state carry (asm outputs)
    float4 d0, d1, d2, d3, d4;   // h1-state carry
    float  xt;

    // preA (7 ops): write h0[0]; read h0-state; read x[1]
    asm volatile(
        "ds_write_b32 %7, %8\n\t"
        "ds_read_b128 %0, %6 offset:0\n\t"
        "ds_read_b128 %1, %6 offset:16\n\t"
        "ds_read_b128 %2, %6 offset:32\n\t"
        "ds_read_b128 %3, %6 offset:48\n\t"
        "ds_read_b128 %4, %6 offset:64\n\t"
        "ds_read_b32  %5, %9\n\t"
        : "=&v"(c0), "=&v"(c1), "=&v"(c2), "=&v"(c3), "=&v"(c4), "=&v"(xt)
        : "v"(h0_base), "v"(h0_mine), "v"(n0_keep),
          "v"((uint32_t)(uintptr_t)&xs[g][1])
        : "memory");
    // preB (5 ops): read h1-state (h1[-1], already written above)
    asm volatile(
        "ds_read_b128 %0, %5 offset:0\n\t"
        "ds_read_b128 %1, %5 offset:16\n\t"
        "ds_read_b128 %2, %5 offset:32\n\t"
        "ds_read_b128 %3, %5 offset:48\n\t"
        "ds_read_b128 %4, %5 offset:64\n\t"
        : "=&v"(d0), "=&v"(d1), "=&v"(d2), "=&v"(d3), "=&v"(d4)
        : "v"(h1_base)
        : "memory");
    // finish preA (leave preB's 5 in flight)
    asm volatile("s_waitcnt lgkmcnt(5)" ::: "memory");
    __builtin_amdgcn_sched_barrier(0);

    float n1_keep = 0.f;
    // ---- main loop i=1..511: entry: c=h0[i-1] (ready), d=h1[i-2] (in
    // flight, ready after mid-wait), xt=x[i] (ready).
    #pragma unroll 1
    for (int i = 1; i < Tn; ++i) {
        // layer0 + layer1-input dots (both use c = h0[i-1])
        v2 a0  = (v2){fmaf(xt, wih0, bias0), 0.f};
        v2 a0b = (v2){0.f, 0.f};
        v2 a1  = (v2){bias1, 0.f};
        v2 a1b = (v2){0.f, 0.f};
        DOT20Q(a0, a0b, w0, c0, c1, c2, c3, c4);
        DOT20Q(a1, a1b, w1, c0, c1, c2, c3, c4);
        const v2 s0 = a0 + a0b;
        const float n0 = tanh_fast(s0.x + s0.y);
        n0_keep = n0;

        // A-block (7): write h0[i]; read h0-state back; read x[i+1]
        asm volatile(
            "ds_write_b32 %7, %8\n\t"
            "ds_read_b128 %0, %6 offset:0\n\t"
            "ds_read_b128 %1, %6 offset:16\n\t"
            "ds_read_b128 %2, %6 offset:32\n\t"
            "ds_read_b128 %3, %6 offset:48\n\t"
            "ds_read_b128 %4, %6 offset:64\n\t"
            "ds_read_b32  %5, %9\n\t"
            : "=&v"(c0), "=&v"(c1), "=&v"(c2), "=&v"(c3), "=&v"(c4), "=&v"(xt)
            : "v"(h0_base), "v"(h0_mine), "v"(n0), "v"(x_addr)
            : "memory");
        x_addr += 4;

        // prev B-block (d = h1[i-2]) completed; A's 7 stay in flight
        asm volatile("s_waitcnt lgkmcnt(7)" ::: "memory");
        __builtin_amdgcn_sched_barrier(0);

        // layer1 recurrent dot (uses d) + finish h1[i-1]
        v2 a2  = (v2){0.f, 0.f};
        v2 a2b = (v2){0.f, 0.f};
        DOT20Q(a2, a2b, w2, d0, d1, d2, d3, d4);
        const v2 s1 = (a1 + a1b) + (a2 + a2b);
        const float n1 = tanh_fast(s1.x + s1.y);
        n1_keep = n1;

        // B-block (6): write h1[i-1]; read h1-state back
        asm volatile(
            "ds_write_b32 %5, %6\n\t"
            "ds_read_b128 %0, %7 offset:0\n\t"
            "ds_read_b128 %1, %7 offset:16\n\t"
            "ds_read_b128 %2, %7 offset:32\n\t"
            "ds_read_b128 %3, %7 offset:48\n\t"
            "ds_read_b128 %4, %7 offset:64\n\t"
            : "=&v"(d0), "=&v"(d1), "=&v"(d2), "=&v"(d3), "=&v"(d4)
            : "v"(h1_mine), "v"(n1), "v"(h1_base)
            : "memory");

        // A-block done (c, xt ready for next iter); B's 6 stay in flight
        asm volatile("s_waitcnt lgkmcnt(6)" ::: "memory");
        __builtin_amdgcn_sched_barrier(0);
    }

    // ---- epilogue: drain B (d = h1[510]); compute h1[511]
    asm volatile("s_waitcnt lgkmcnt(0)" ::: "memory");
    __builtin_amdgcn_sched_barrier(0);
    float n1_last;
    {
        v2 a1  = (v2){bias1, 0.f};
        v2 a1b = (v2){0.f, 0.f};
        v2 a2  = (v2){0.f, 0.f};
        v2 a2b = (v2){0.f, 0.f};
        DOT20Q(a1, a1b, w1, c0, c1, c2, c3, c4);   // c = h0[511]
        DOT20Q(a2, a2b, w2, d0, d1, d2, d3, d4);   // d = h1[510]
        const v2 s1 = (a1 + a1b) + (a2 + a2b);
        n1_last = tanh_fast(s1.x + s1.y);
    }
    hs[1][g][j] = n1_last;             // for the fc-head gather (in-order)

    // ---- outputs
    if (store_ok) {
        out[Bsz + (long)b * Hn + j]                  = n0_keep;   // h0[511]
        out[Bsz + (long)Bsz * Hn + (long)b * Hn + j] = n1_last;   // h1[511]
        if (j == 0) {                  // fc head: one lane per batch
            LOAD_ROWP(fw, fc_w)
            const float4 v0 = *(const float4*)&hs[1][g][0];
            const float4 v1 = *(const float4*)&hs[1][g][4];
            const float4 v2q = *(const float4*)&hs[1][g][8];
            const float4 v3 = *(const float4*)&hs[1][g][12];
            const float4 v4 = *(const float4*)&hs[1][g][16];
            v2 aA = (v2){fc_b[0], 0.f};
            v2 aB = (v2){0.f, 0.f};
            DOT20Q(aA, aB, fw, v0, v1, v2q, v3, v4);
            const v2 s = aA + aB;
            out[b] = s.x + s.y;
        }
    }
    (void)n1_keep;
}

extern "C" void kernel_launch(void* const* d_in, const int* in_sizes, int n_in,
                              void* d_out, int out_size, void* d_ws, size_t ws_size,
                              hipStream_t stream) {
    const float* x      = (const float*)d_in[0];
    const float* hidden = (const float*)d_in[1];
    const float* W_ih0  = (const float*)d_in[2];
    const float* W_hh0  = (const float*)d_in[3];
    const float* b_ih0  = (const float*)d_in[4];
    const float* b_hh0  = (const float*)d_in[5];
    const float* W_ih1  = (const float*)d_in[6];
    const float* W_hh1  = (const float*)d_in[7];
    const float* b_ih1  = (const float*)d_in[8];
    const float* b_hh1  = (const float*)d_in[9];
    const float* fc_w   = (const float*)d_in[10];
    const float* fc_b   = (const float*)d_in[11];

    const int nblocks = (Bsz + GB - 1) / GB;   // 1366
    rnn2_fused<<<nblocks, NTHREADS, 0, stream>>>(
        x, hidden, W_ih0, W_hh0, b_ih0, b_hh0,
        W_ih1, W_hh1, b_ih1, b_hh1, fc_w, fc_b, (float*)d_out);
}

// Round 19
// 133.528 us; speedup vs baseline: 1.5859x; 1.5859x over previous
//
#include <hip/hip_runtime.h>

// 2-layer tanh RNN, fused, f32, PRODUCER-CONSUMER 2-WAVE BLOCKS. GB=3.
// B=4096, T=512, H=20.
// R19 model (R13-R18): wall = 512 x per-wave chain ~600cyc. The chain in a
// single-wave design includes ~140cyc of layer1 ISSUE between the h0 read
// and h0 write (one wave = one instruction stream). Split: wave0 = layer0
// only (chain: read h0 -> 10 pk_fma -> tanh -> write, ~25 instr), wave1 =
// layer1 one step behind. __syncthreads() once per iter (uniform flow);
// h0 double-buffered across waves; h1 private to wave1 (in-order DS).
// 1366 blocks x 2 waves = 2732 waves = 2.67/SIMD.

#define Bsz 4096
#define Tn  512
#define Hn  20
#define GB  3
#define XPAD 520
#define NTHREADS 128

typedef float v2 __attribute__((ext_vector_type(2)));

__device__ __forceinline__ float tanh_fast(float v) {
    // tanh(v) = 1 - 2/(exp(2v)+1); v_exp_f32 + v_rcp_f32.
    float e = __expf(2.0f * v);
    return 1.0f - 2.0f * __builtin_amdgcn_rcpf(e + 1.0f);
}

// packed 20-dot: 10 v_pk_fma_f32, two chains
#define DOT20P(acc, accb, W, H) do { \
    acc  = __builtin_elementwise_fma(W##0, H##0, acc);  \
    accb = __builtin_elementwise_fma(W##1, H##1, accb); \
    acc  = __builtin_elementwise_fma(W##2, H##2, acc);  \
    accb = __builtin_elementwise_fma(W##3, H##3, accb); \
    acc  = __builtin_elementwise_fma(W##4, H##4, acc);  \
    accb = __builtin_elementwise_fma(W##5, H##5, accb); \
    acc  = __builtin_elementwise_fma(W##6, H##6, acc);  \
    accb = __builtin_elementwise_fma(W##7, H##7, accb); \
    acc  = __builtin_elementwise_fma(W##8, H##8, acc);  \
    accb = __builtin_elementwise_fma(W##9, H##9, accb); \
} while (0)

#define LOAD_ROWP(W, ptr) \
    v2 W##0, W##1, W##2, W##3, W##4, W##5, W##6, W##7, W##8, W##9; \
    { const float4* _p = (const float4*)(ptr); \
      float4 _t; \
      _t = _p[0]; W##0 = (v2){_t.x, _t.y}; W##1 = (v2){_t.z, _t.w}; \
      _t = _p[1]; W##2 = (v2){_t.x, _t.y}; W##3 = (v2){_t.z, _t.w}; \
      _t = _p[2]; W##4 = (v2){_t.x, _t.y}; W##5 = (v2){_t.z, _t.w}; \
      _t = _p[3]; W##6 = (v2){_t.x, _t.y}; W##7 = (v2){_t.z, _t.w}; \
      _t = _p[4]; W##8 = (v2){_t.x, _t.y}; W##9 = (v2){_t.z, _t.w}; }

#define READ_H(H, base) \
    v2 H##0, H##1, H##2, H##3, H##4, H##5, H##6, H##7, H##8, H##9; \
    { const float4 _a = *(const float4*)((base) + 0);  \
      const float4 _b = *(const float4*)((base) + 4);  \
      const float4 _c = *(const float4*)((base) + 8);  \
      const float4 _d = *(const float4*)((base) + 12); \
      const float4 _e = *(const float4*)((base) + 16); \
      H##0 = (v2){_a.x, _a.y}; H##1 = (v2){_a.z, _a.w}; \
      H##2 = (v2){_b.x, _b.y}; H##3 = (v2){_b.z, _b.w}; \
      H##4 = (v2){_c.x, _c.y}; H##5 = (v2){_c.z, _c.w}; \
      H##6 = (v2){_d.x, _d.y}; H##7 = (v2){_d.z, _d.w}; \
      H##8 = (v2){_e.x, _e.y}; H##9 = (v2){_e.z, _e.w}; }

__global__ __launch_bounds__(NTHREADS)
__attribute__((amdgpu_waves_per_eu(1, 4)))
void rnn2_fused(const float* __restrict__ x,        // [B,T,1]
                const float* __restrict__ hidden,   // [2,B,H]
                const float* __restrict__ W_ih0,    // [H,1]
                const float* __restrict__ W_hh0,    // [H,H]
                const float* __restrict__ b_ih0,    // [H]
                const float* __restrict__ b_hh0,    // [H]
                const float* __restrict__ W_ih1,    // [H,H]
                const float* __restrict__ W_hh1,    // [H,H]
                const float* __restrict__ b_ih1,    // [H]
                const float* __restrict__ b_hh1,    // [H]
                const float* __restrict__ fc_w,     // [1,H]
                const float* __restrict__ fc_b,     // [1]
                float* __restrict__ out)            // [B] ++ [2,B,H] flat
{
    const int tid  = threadIdx.x;
    const int wave = tid >> 6;         // 0 = layer0 producer, 1 = layer1
    const int lane = tid & 63;
    int g = lane / Hn;                 // 0..3
    int j = lane - g * Hn;             // 0..19
    const bool lane_ok = (lane < GB * Hn);
    if (!lane_ok) { g = GB - 1; j = lane - 60; }  // dup lanes: benign

    const int  b        = blockIdx.x * GB + g;
    const bool b_ok     = (b < Bsz);
    const int  bl       = b_ok ? b : (Bsz - 1);
    const bool store_ok = lane_ok && b_ok;

    __shared__ float xs[GB][XPAD];     // 6.24 KB (padded: conflict-free)
    __shared__ float h0s[2][GB][Hn];   // double-buffered, cross-wave
    __shared__ float h1s[GB][Hn];      // wave1-private (in-order DS)

    // wave0 uses wA = W_hh0 row; wave1 uses wA = W_ih1, wB = W_hh1 rows.
    const float* rowA = (wave == 0) ? (W_hh0 + j * Hn) : (W_ih1 + j * Hn);
    LOAD_ROWP(wA, rowA)
    LOAD_ROWP(wB, W_hh1 + j * Hn)      // used by wave1 only

    const float wih0  = W_ih0[j];
    const float bias0 = b_ih0[j] + b_hh0[j];
    const float bias1 = b_ih1[j] + b_hh1[j];

    // ---- stage ALL x with all 128 threads (coalesced float4)
    {
        const int bB = blockIdx.x * GB;
        #pragma unroll
        for (int r = 0; r < (GB * Tn) / (NTHREADS * 4); ++r) {  // 3 rounds
            const int c  = (r * NTHREADS + tid) * 4;
            const int gg = c >> 9;
            const int t  = c & (Tn - 1);
            const int bb = (bB + gg < Bsz) ? (bB + gg) : (Bsz - 1);
            float4 v = *(const float4*)(x + (long)bb * Tn + t);
            *(float4*)&xs[gg][t] = v;
        }
    }

    // ---- init: h0[-1] -> buf1 (iter0 reads p=(0+1)&1=1); h1[-1] -> h1s
    if (wave == 0) h0s[1][g][j] = hidden[bl * Hn + j];
    else           h1s[g][j]    = hidden[(long)Bsz * Hn + bl * Hn + j];
    __syncthreads();

    float n_keep = 0.f;   // wave0: h0[i]; wave1: h1[i-1]

    // ---- main loop: iter i: wave0 computes h0[i] (reads buf p, writes
    // buf q); wave1 computes h1[i-1] for i>0 (reads buf p + own h1s).
    #pragma unroll 2
    for (int i = 0; i < Tn; ++i) {
        const int p = (i + 1) & 1, q = i & 1;
        if (wave == 0) {
            READ_H(hA, &h0s[p][g][0])
            const float xt = xs[g][i];
            v2 a  = (v2){fmaf(xt, wih0, bias0), 0.f};
            v2 ab = (v2){0.f, 0.f};
            DOT20P(a, ab, wA, hA);
            const v2 s = a + ab;
            const float n = tanh_fast(s.x + s.y);
            h0s[q][g][j] = n;
            n_keep = n;
        } else if (i > 0) {
            READ_H(hA, &h0s[p][g][0])     // h0[i-1]
            READ_H(hB, &h1s[g][0])        // h1[i-2] (own, in-order)
            v2 a1  = (v2){bias1, 0.f};
            v2 a1b = (v2){0.f, 0.f};
            v2 a2  = (v2){0.f, 0.f};
            v2 a2b = (v2){0.f, 0.f};
            DOT20P(a1, a1b, wA, hA);
            DOT20P(a2, a2b, wB, hB);
            const v2 s = (a1 + a1b) + (a2 + a2b);
            const float n = tanh_fast(s.x + s.y);
            h1s[g][j] = n;                // h1[i-1]
            n_keep = n;
        }
        __syncthreads();   // uniform flow; publishes h0[i] to wave1
    }

    // ---- epilogue + outputs
    if (wave == 0) {
        if (store_ok)
            out[Bsz + (long)b * Hn + j] = n_keep;          // new_hidden[0]
    } else {
        // h1[511] = tanh(W_ih1 h0[511] + b1 + W_hh1 h1[510])
        READ_H(hA, &h0s[1][g][0])        // h0[511] in buf (511&1)=1
        READ_H(hB, &h1s[g][0])           // h1[510]
        v2 a1  = (v2){bias1, 0.f};
        v2 a1b = (v2){0.f, 0.f};
        v2 a2  = (v2){0.f, 0.f};
        v2 a2b = (v2){0.f, 0.f};
        DOT20P(a1, a1b, wA, hA);
        DOT20P(a2, a2b, wB, hB);
        const v2 s = (a1 + a1b) + (a2 + a2b);
        const float n1_last = tanh_fast(s.x + s.y);
        h1s[g][j] = n1_last;             // for fc gather (own, in-order)

        if (store_ok) {
            out[Bsz + (long)Bsz * Hn + (long)b * Hn + j] = n1_last;
            if (j == 0) {                // fc head: one lane per batch
                LOAD_ROWP(fw, fc_w)
                READ_H(hv, &h1s[g][0])
                v2 aA = (v2){fc_b[0], 0.f};
                v2 aB = (v2){0.f, 0.f};
                DOT20P(aA, aB, fw, hv);
                const v2 sf = aA + aB;
                out[b] = sf.x + sf.y;
            }
        }
    }
}

extern "C" void kernel_launch(void* const* d_in, const int* in_sizes, int n_in,
                              void* d_out, int out_size, void* d_ws, size_t ws_size,
                              hipStream_t stream) {
    const float* x      = (const float*)d_in[0];
    const float* hidden = (const float*)d_in[1];
    const float* W_ih0  = (const float*)d_in[2];
    const float* W_hh0  = (const float*)d_in[3];
    const float* b_ih0  = (const float*)d_in[4];
    const float* b_hh0  = (const float*)d_in[5];
    const float* W_ih1  = (const float*)d_in[6];
    const float* W_hh1  = (const float*)d_in[7];
    const float* b_ih1  = (const float*)d_in[8];
    const float* b_hh1  = (const float*)d_in[9];
    const float* fc_w   = (const float*)d_in[10];
    const float* fc_b   = (const float*)d_in[11];

    const int nblocks = (Bsz + GB - 1) / GB;   // 1366
    rnn2_fused<<<nblocks, NTHREADS, 0, stream>>>(
        x, hidden, W_ih0, W_hh0, b_ih0, b_hh0,
        W_ih1, W_hh1, b_ih1, b_hh1, fc_w, fc_b, (float*)d_out);
}

// Round 20
// 128.121 us; speedup vs baseline: 1.6529x; 1.0422x over previous
//
#include <hip/hip_runtime.h>

// 2-layer tanh RNN, fused, f32, PHASED producer-consumer, 2-wave blocks.
// B=4096, T=512, H=20, GB=3.
// R20: R19's layer-split but synchronized per PHASE (K=8 steps), not per
// step. h0 flows through a 16-slot LDS ring; phase k: wave0 writes slots
// {8k..8k+7} mod 16 (one half), wave1 reads the OTHER half (steps of
// phase k-1) -> race-free by construction; barrier once per phase
// (~12cyc/iter amortized vs ~2 barriers/iter in R19).
// Each wave's per-iter chain is now only its own tanh + LDS round trip
// (~300cyc), and the two chains run concurrently; layer1's h0 reads are
// dependency-free (pre-written a phase ago) so the compiler can hoist
// them. h1 is wave1-private (single-wave in-order DS, no barrier).

#define Bsz 4096
#define Tn  512
#define Hn  20
#define GB  3
#define K   8                  // steps per phase
#define RING 16                // 2 phases of h0 slots
#define NPH (Tn / K)           // 64 producer phases
#define XPAD 520
#define NTHREADS 128

typedef float v2 __attribute__((ext_vector_type(2)));

__device__ __forceinline__ float tanh_fast(float v) {
    // tanh(v) = 1 - 2/(exp(2v)+1); v_exp_f32 + v_rcp_f32.
    float e = __expf(2.0f * v);
    return 1.0f - 2.0f * __builtin_amdgcn_rcpf(e + 1.0f);
}

// packed 20-dot: 10 v_pk_fma_f32, two chains
#define DOT20P(acc, accb, W, H) do { \
    acc  = __builtin_elementwise_fma(W##0, H##0, acc);  \
    accb = __builtin_elementwise_fma(W##1, H##1, accb); \
    acc  = __builtin_elementwise_fma(W##2, H##2, acc);  \
    accb = __builtin_elementwise_fma(W##3, H##3, accb); \
    acc  = __builtin_elementwise_fma(W##4, H##4, acc);  \
    accb = __builtin_elementwise_fma(W##5, H##5, accb); \
    acc  = __builtin_elementwise_fma(W##6, H##6, acc);  \
    accb = __builtin_elementwise_fma(W##7, H##7, accb); \
    acc  = __builtin_elementwise_fma(W##8, H##8, acc);  \
    accb = __builtin_elementwise_fma(W##9, H##9, accb); \
} while (0)

#define LOAD_ROWP(W, ptr) \
    v2 W##0, W##1, W##2, W##3, W##4, W##5, W##6, W##7, W##8, W##9; \
    { const float4* _p = (const float4*)(ptr); \
      float4 _t; \
      _t = _p[0]; W##0 = (v2){_t.x, _t.y}; W##1 = (v2){_t.z, _t.w}; \
      _t = _p[1]; W##2 = (v2){_t.x, _t.y}; W##3 = (v2){_t.z, _t.w}; \
      _t = _p[2]; W##4 = (v2){_t.x, _t.y}; W##5 = (v2){_t.z, _t.w}; \
      _t = _p[3]; W##6 = (v2){_t.x, _t.y}; W##7 = (v2){_t.z, _t.w}; \
      _t = _p[4]; W##8 = (v2){_t.x, _t.y}; W##9 = (v2){_t.z, _t.w}; }

#define READ_H(H, base) \
    v2 H##0, H##1, H##2, H##3, H##4, H##5, H##6, H##7, H##8, H##9; \
    { const float4 _a = *(const float4*)((base) + 0);  \
      const float4 _b = *(const float4*)((base) + 4);  \
      const float4 _c = *(const float4*)((base) + 8);  \
      const float4 _d = *(const float4*)((base) + 12); \
      const float4 _e = *(const float4*)((base) + 16); \
      H##0 = (v2){_a.x, _a.y}; H##1 = (v2){_a.z, _a.w}; \
      H##2 = (v2){_b.x, _b.y}; H##3 = (v2){_b.z, _b.w}; \
      H##4 = (v2){_c.x, _c.y}; H##5 = (v2){_c.z, _c.w}; \
      H##6 = (v2){_d.x, _d.y}; H##7 = (v2){_d.z, _d.w}; \
      H##8 = (v2){_e.x, _e.y}; H##9 = (v2){_e.z, _e.w}; }

__global__ __launch_bounds__(NTHREADS)
__attribute__((amdgpu_waves_per_eu(1, 4)))
void rnn2_fused(const float* __restrict__ x,        // [B,T,1]
                const float* __restrict__ hidden,   // [2,B,H]
                const float* __restrict__ W_ih0,    // [H,1]
                const float* __restrict__ W_hh0,    // [H,H]
                const float* __restrict__ b_ih0,    // [H]
                const float* __restrict__ b_hh0,    // [H]
                const float* __restrict__ W_ih1,    // [H,H]
                const float* __restrict__ W_hh1,    // [H,H]
                const float* __restrict__ b_ih1,    // [H]
                const float* __restrict__ b_hh1,    // [H]
                const float* __restrict__ fc_w,     // [1,H]
                const float* __restrict__ fc_b,     // [1]
                float* __restrict__ out)            // [B] ++ [2,B,H] flat
{
    const int tid  = threadIdx.x;
    const int wave = tid >> 6;         // 0 = layer0 producer, 1 = layer1
    const int lane = tid & 63;
    int g = lane / Hn;                 // 0..3
    int j = lane - g * Hn;             // 0..19
    const bool lane_ok = (lane < GB * Hn);
    if (!lane_ok) { g = GB - 1; j = lane - 60; }  // dup lanes: benign

    const int  b        = blockIdx.x * GB + g;
    const bool b_ok     = (b < Bsz);
    const int  bl       = b_ok ? b : (Bsz - 1);
    const bool store_ok = lane_ok && b_ok;

    __shared__ float xs[GB][XPAD];         // 6.24 KB
    __shared__ float h0r[RING][GB][Hn];    // h0 ring, cross-wave (3.84 KB)
    __shared__ float h1s[GB][Hn];          // wave1-private

    // wave0: wA = W_hh0 row. wave1: wA = W_ih1 row, wB = W_hh1 row.
    const float* rowA = (wave == 0) ? (W_hh0 + j * Hn) : (W_ih1 + j * Hn);
    LOAD_ROWP(wA, rowA)
    LOAD_ROWP(wB, W_hh1 + j * Hn)          // live only in wave1

    const float wih0  = W_ih0[j];
    const float bias0 = b_ih0[j] + b_hh0[j];
    const float bias1 = b_ih1[j] + b_hh1[j];

    // ---- stage ALL x with 128 threads (coalesced float4)
    {
        const int bB = blockIdx.x * GB;
        #pragma unroll
        for (int r = 0; r < (GB * Tn) / (NTHREADS * 4); ++r) {  // 3 rounds
            const int c  = (r * NTHREADS + tid) * 4;
            const int gg = c >> 9;
            const int t  = c & (Tn - 1);
            const int bb = (bB + gg < Bsz) ? (bB + gg) : (Bsz - 1);
            float4 v = *(const float4*)(x + (long)bb * Tn + t);
            *(float4*)&xs[gg][t] = v;
        }
    }

    // ---- init: h0[-1] -> ring slot 15 (t=0 reads slot (0-1)&15 = 15);
    //            h1[-1] -> h1s
    if (wave == 0) h0r[RING - 1][g][j] = hidden[bl * Hn + j];
    else           h1s[g][j]           = hidden[(long)Bsz * Hn + bl * Hn + j];
    __syncthreads();   // publish xs + inits

    float n_keep = 0.f;   // wave0: ends as h0[511]; wave1: ends as h1[511]

    // ---- phases: k=0..NPH. wave0 active k<NPH (steps 8k..8k+7 -> half
    // (k&1) of the ring). wave1 active k>0 (steps 8(k-1)..8k-1, reading
    // half ((k-1)&1) -- the OTHER half). Barrier between phases.
    for (int k = 0; k <= NPH; ++k) {
        if (wave == 0) {
            if (k < NPH) {
                #pragma unroll
                for (int u = 0; u < K; ++u) {
                    const int t = k * K + u;
                    READ_H(hA, &h0r[(t - 1) & (RING - 1)][g][0])  // h0[t-1]
                    const float xt = xs[g][t];
                    v2 a  = (v2){fmaf(xt, wih0, bias0), 0.f};
                    v2 ab = (v2){0.f, 0.f};
                    DOT20P(a, ab, wA, hA);
                    const v2 s = a + ab;
                    const float n = tanh_fast(s.x + s.y);
                    h0r[t & (RING - 1)][g][j] = n;
                    n_keep = n;
                }
            }
        } else {
            if (k > 0) {
                #pragma unroll
                for (int u = 0; u < K; ++u) {
                    const int t = (k - 1) * K + u;
                    READ_H(hA, &h0r[t & (RING - 1)][g][0])  // h0[t], pre-written
                    READ_H(hB, &h1s[g][0])                  // h1[t-1], own
                    v2 a1  = (v2){bias1, 0.f};
                    v2 a1b = (v2){0.f, 0.f};
                    v2 a2  = (v2){0.f, 0.f};
                    v2 a2b = (v2){0.f, 0.f};
                    DOT20P(a1, a1b, wA, hA);
                    DOT20P(a2, a2b, wB, hB);
                    const v2 s = (a1 + a1b) + (a2 + a2b);
                    const float n = tanh_fast(s.x + s.y);
                    h1s[g][j] = n;                          // h1[t]
                    n_keep = n;
                }
            }
        }
        if (k < NPH) __syncthreads();   // uniform (k is block-uniform)
    }

    // ---- outputs
    if (wave == 0) {
        if (store_ok)
            out[Bsz + (long)b * Hn + j] = n_keep;             // h0[511]
    } else {
        if (store_ok) {
            out[Bsz + (long)Bsz * Hn + (long)b * Hn + j] = n_keep;  // h1[511]
            if (j == 0) {                // fc head: one lane per batch
                LOAD_ROWP(fw, fc_w)
                READ_H(hv, &h1s[g][0])   // own-wave in-order
                v2 aA = (v2){fc_b[0], 0.f};
                v2 aB = (v2){0.f, 0.f};
                DOT20P(aA, aB, fw, hv);
                const v2 sf = aA + aB;
                out[b] = sf.x + sf.y;
            }
        }
    }
}

extern "C" void kernel_launch(void* const* d_in, const int* in_sizes, int n_in,
                              void* d_out, int out_size, void* d_ws, size_t ws_size,
                              hipStream_t stream) {
    const float* x      = (const float*)d_in[0];
    const float* hidden = (const float*)d_in[1];
    const float* W_ih0  = (const float*)d_in[2];
    const float* W_hh0  = (const float*)d_in[3];
    const float* b_ih0  = (const float*)d_in[4];
    const float* b_hh0  = (const float*)d_in[5];
    const float* W_ih1  = (const float*)d_in[6];
    const float* W_hh1  = (const float*)d_in[7];
    const float* b_ih1  = (const float*)d_in[8];
    const float* b_hh1  = (const float*)d_in[9];
    const float* fc_w   = (const float*)d_in[10];
    const float* fc_b   = (const float*)d_in[11];

    const int nblocks = (Bsz + GB - 1) / GB;   // 1366
    rnn2_fused<<<nblocks, NTHREADS, 0, stream>>>(
        x, hidden, W_ih0, W_hh0, b_ih0, b_hh0,
        W_ih1, W_hh1, b_ih1, b_hh1, fc_w, fc_b, (float*)d_out);
}